// Round 5
// baseline (426.032 us; speedup 1.0000x reference)
//
#include <hip/hip_runtime.h>
#include <hip/hip_bf16.h>

// Problem: B=4, N=2048, H=16, Dh=64, D=1024. All global tensors fp32.
// out = LN( softmax(Q K^T / 8) V @ W_out^T ) * g   (fp32 out).
// R5: XOR-swizzled LDS (no pad), V^T staging (b128 frags), 128-query blocks.

#define Bv 4
#define Nv 2048
#define Hv 16
#define DHv 64
#define Dv 1024

typedef __attribute__((ext_vector_type(8))) short short8;
typedef __attribute__((ext_vector_type(4))) float floatx4;

__device__ inline unsigned pack_bf2(float a, float b) {
    unsigned short ua = __builtin_bit_cast(unsigned short, __float2bfloat16(a));
    unsigned short ub = __builtin_bit_cast(unsigned short, __float2bfloat16(b));
    return (unsigned)ua | ((unsigned)ub << 16);
}

// Swizzled offset for 64-col bf16 tiles (8 x 16B blocks per row):
//   addr_shorts(row, col) = row*64 + ((cb ^ s) << 3) + (col & 7),  cb = col>>3
// K/Q use s = row & 7; V^T uses s = (row>>1) & 7.

// ---------------------------------------------------------------------------
// MFMA flash attention. Block = 256 thr (4 waves) = 128 queries of one (b,h).
// Wave w owns q-sets {w*32 + qs*16 + lr : qs in 0,1}.
// Per 64-key tile: S^T = K·Q^T (8 MFMA/qs), online softmax, P gathered to
// A-layout via in-wave shuffles, O += P·V with V^T b128 frags.
// ---------------------------------------------------------------------------
__global__ __launch_bounds__(256)
void attn_mfma(const float* __restrict__ q,
               const float* __restrict__ k,
               const float* __restrict__ v,
               __hip_bfloat16* __restrict__ out) {
    __shared__ __align__(16) short Qs[128 * 64];  // 16 KB, swizzle row&7
    __shared__ __align__(16) short Kt[64 * 64];   //  8 KB, swizzle row&7
    __shared__ __align__(16) short Vt[64 * 64];   //  8 KB, V^T rows=d, swizzle (d>>1)&7

    const int t = threadIdx.x;
    const int wave = t >> 6, lane = t & 63;
    const int quad = lane >> 4, lr = lane & 15;
    const int b = blockIdx.z, h = blockIdx.y;
    const int q0 = blockIdx.x * 128;
    const size_t bh = ((size_t)b * Nv) * Dv + h * DHv;

    // ---- stage Q (x 0.125 exact), swizzled ----
#pragma unroll
    for (int p = 0; p < 4; ++p) {
        int idx = p * 256 + t;
        int r = idx >> 3, cb = idx & 7;
        const float4* src = (const float4*)(q + bh + (size_t)(q0 + r) * Dv + cb * 8);
        float4 a = src[0], c = src[1];
        uint4 u;
        u.x = pack_bf2(a.x * 0.125f, a.y * 0.125f);
        u.y = pack_bf2(a.z * 0.125f, a.w * 0.125f);
        u.z = pack_bf2(c.x * 0.125f, c.y * 0.125f);
        u.w = pack_bf2(c.z * 0.125f, c.w * 0.125f);
        *(uint4*)&Qs[r * 64 + ((cb ^ (r & 7)) << 3)] = u;
    }
    __syncthreads();
    short8 qfrag[2][2];   // [qs][kh]: Q[q = w*32+qs*16+lr][d = 32kh+8quad+j]
#pragma unroll
    for (int qs = 0; qs < 2; ++qs)
#pragma unroll
        for (int kh = 0; kh < 2; ++kh) {
            int row = wave * 32 + qs * 16 + lr;
            qfrag[qs][kh] = *(const short8*)&Qs[row * 64 + (((kh * 4 + quad) ^ (lr & 7)) << 3)];
        }

    floatx4 o_acc[2][4] = {};        // [qs][td]: O[q=4quad+r][d=16td+lr]
    float mrow[2] = {-INFINITY, -INFINITY};
    float lrow[2] = {0.f, 0.f};

    const int srcA = ((2 * (quad & 1)) << 4) | lr;   // P-gather source lanes
    const int srcB = srcA + 16;
    const bool hi = (quad >= 2);

    for (int k0 = 0; k0 < Nv; k0 += 64) {
        __syncthreads();
        // ---- stage K (swizzle row&7) ----
#pragma unroll
        for (int p = 0; p < 2; ++p) {
            int idx = p * 256 + t;
            int r = idx >> 3, cb = idx & 7;
            const float4* src = (const float4*)(k + bh + (size_t)(k0 + r) * Dv + cb * 8);
            float4 a = src[0], c = src[1];
            uint4 u;
            u.x = pack_bf2(a.x, a.y); u.y = pack_bf2(a.z, a.w);
            u.z = pack_bf2(c.x, c.y); u.w = pack_bf2(c.z, c.w);
            *(uint4*)&Kt[r * 64 + ((cb ^ (r & 7)) << 3)] = u;
        }
        // ---- stage V^T: rows = d, cols = key-pairs (u32), swizzle (d>>1)&7 ----
#pragma unroll
        for (int p = 0; p < 2; ++p) {
            int idx = p * 256 + t;
            int dq = idx & 15, rr = idx >> 4;   // d-quad, key-pair
            const float* vp = v + bh + (size_t)(k0 + 2 * rr) * Dv + dq * 4;
            float4 v0 = *(const float4*)vp;
            float4 v1 = *(const float4*)(vp + Dv);
            float va[4] = {v0.x, v0.y, v0.z, v0.w};
            float vb[4] = {v1.x, v1.y, v1.z, v1.w};
#pragma unroll
            for (int i = 0; i < 4; ++i) {
                int d = dq * 4 + i;
                ((unsigned*)Vt)[d * 32 + (((rr >> 2) ^ ((d >> 1) & 7)) << 2) + (rr & 3)] =
                    pack_bf2(va[i], vb[i]);
            }
        }
        __syncthreads();

        // ---- S^T = K·Q^T (K-frags read once, used by both q-sets) ----
        floatx4 s_acc[2][4] = {};
#pragma unroll
        for (int tt = 0; tt < 4; ++tt) {
            int row = tt * 16 + lr;
            short8 kf0 = *(const short8*)&Kt[row * 64 + ((quad ^ (lr & 7)) << 3)];
            short8 kf1 = *(const short8*)&Kt[row * 64 + (((4 + quad) ^ (lr & 7)) << 3)];
#pragma unroll
            for (int qs = 0; qs < 2; ++qs) {
                s_acc[qs][tt] = __builtin_amdgcn_mfma_f32_16x16x32_bf16(kf0, qfrag[qs][0], s_acc[qs][tt], 0, 0, 0);
                s_acc[qs][tt] = __builtin_amdgcn_mfma_f32_16x16x32_bf16(kf1, qfrag[qs][1], s_acc[qs][tt], 0, 0, 0);
            }
        }

        // ---- online softmax + P pack, per q-set ----
        unsigned p2[2][8];
#pragma unroll
        for (int qs = 0; qs < 2; ++qs) {
            float tmax = -INFINITY;
#pragma unroll
            for (int tt = 0; tt < 4; ++tt)
#pragma unroll
                for (int r2 = 0; r2 < 4; ++r2) tmax = fmaxf(tmax, s_acc[qs][tt][r2]);
            tmax = fmaxf(tmax, __shfl_xor(tmax, 16));
            tmax = fmaxf(tmax, __shfl_xor(tmax, 32));
            float mnew = fmaxf(mrow[qs], tmax);
            float alpha = __expf(mrow[qs] - mnew);   // first tile: exp(-inf)=0
            mrow[qs] = mnew;
            float psum = 0.f;
#pragma unroll
            for (int tt = 0; tt < 4; ++tt)
#pragma unroll
                for (int r2 = 0; r2 < 4; ++r2) {
                    float p = __expf(s_acc[qs][tt][r2] - mnew);
                    s_acc[qs][tt][r2] = p;
                    psum += p;
                }
            psum += __shfl_xor(psum, 16);
            psum += __shfl_xor(psum, 32);
            lrow[qs] = lrow[qs] * alpha + psum;
            // rescale O rows (queries 4quad+r2)
#pragma unroll
            for (int r2 = 0; r2 < 4; ++r2) {
                float ar = __shfl(alpha, quad * 4 + r2);
#pragma unroll
                for (int td = 0; td < 4; ++td) o_acc[qs][td][r2] *= ar;
            }
#pragma unroll
            for (int tt = 0; tt < 4; ++tt) {
                p2[qs][tt * 2 + 0] = pack_bf2(s_acc[qs][tt][0], s_acc[qs][tt][1]);
                p2[qs][tt * 2 + 1] = pack_bf2(s_acc[qs][tt][2], s_acc[qs][tt][3]);
            }
        }

        // ---- PV: O += P·V  (V^T frags read once, shared by q-sets) ----
#pragma unroll
        for (int kh = 0; kh < 2; ++kh) {
            short8 af[2];
#pragma unroll
            for (int qs = 0; qs < 2; ++qs) {
                int tlo = 4 * kh, thi = 4 * kh + 2;
                unsigned d0a = __shfl(p2[qs][tlo + 0], srcA), d0b = __shfl(p2[qs][thi + 0], srcA);
                unsigned d1a = __shfl(p2[qs][tlo + 1], srcA), d1b = __shfl(p2[qs][thi + 1], srcA);
                unsigned d2a = __shfl(p2[qs][tlo + 0], srcB), d2b = __shfl(p2[qs][thi + 0], srcB);
                unsigned d3a = __shfl(p2[qs][tlo + 1], srcB), d3b = __shfl(p2[qs][thi + 1], srcB);
                int4 afi;
                afi.x = (int)(hi ? d0b : d0a);
                afi.y = (int)(hi ? d1b : d1a);
                afi.z = (int)(hi ? d2b : d2a);
                afi.w = (int)(hi ? d3b : d3a);
                af[qs] = __builtin_bit_cast(short8, afi);
            }
#pragma unroll
            for (int td = 0; td < 4; ++td) {
                int d = td * 16 + lr;
                short8 vf = *(const short8*)&Vt[d * 64 + (((kh * 4 + quad) ^ (lr >> 1)) << 3)];
                o_acc[0][td] = __builtin_amdgcn_mfma_f32_16x16x32_bf16(af[0], vf, o_acc[0][td], 0, 0, 0);
                o_acc[1][td] = __builtin_amdgcn_mfma_f32_16x16x32_bf16(af[1], vf, o_acc[1][td], 0, 0, 0);
            }
        }
    }

    // ---- epilogue: O / l -> bf16 ws (proj A-matrix) ----
#pragma unroll
    for (int qs = 0; qs < 2; ++qs) {
        float linv = 1.f / lrow[qs];
#pragma unroll
        for (int r2 = 0; r2 < 4; ++r2) {
            float lv = __shfl(linv, quad * 4 + r2);
            int row = q0 + wave * 32 + qs * 16 + quad * 4 + r2;
            size_t base = ((size_t)(b * Nv + row)) * Dv + h * DHv;
#pragma unroll
            for (int td = 0; td < 4; ++td)
                out[base + td * 16 + lr] = __float2bfloat16(o_acc[qs][td][r2] * lv);
        }
    }
}

// ---------------------------------------------------------------------------
// Stage 2: C = A @ W^T, 128x128 tile, BK=32, swizzled LDS, 4 waves (2x2).
// A: [8192,1024] bf16 (ws). W: [1024,1024] fp32 -> bf16 in staging.
// C: fp32. Swizzle for 32-col tiles: addr = row*32 + ((cb ^ (row&3))<<3)+(c&7).
// ---------------------------------------------------------------------------
__global__ __launch_bounds__(256)
void proj_kernel(const __hip_bfloat16* __restrict__ A,
                 const float* __restrict__ W,
                 float* __restrict__ C) {
    __shared__ __align__(16) short As[128 * 32];  // 8 KB
    __shared__ __align__(16) short Ws[128 * 32];  // 8 KB

    const int t = threadIdx.x;
    const int wave = t >> 6, lane = t & 63;
    const int quad = lane >> 4, lr = lane & 15;
    const int wm = wave >> 1, wn = wave & 1;
    const int bm = blockIdx.y * 128;
    const int bn = blockIdx.x * 128;

    floatx4 acc[4][4] = {};   // [mb][nb]

    const int rA = t >> 2;          // staging row 0..63? no: 0..63 -> need 128
    const int cbA = t & 3;          // 16B block 0..3

    for (int k0 = 0; k0 < Dv; k0 += 32) {
        __syncthreads();
        // A tile: 128 rows x 32 cols bf16 = 256 16B-blocks; thread does rows rA, rA+64
#pragma unroll
        for (int p = 0; p < 2; ++p) {
            int r = rA + p * 64;
            *(uint4*)&As[r * 32 + ((cbA ^ (r & 3)) << 3)] =
                *(const uint4*)(A + (size_t)(bm + r) * Dv + k0 + cbA * 8);
            const float* wp = W + (size_t)(bn + r) * Dv + k0 + cbA * 8;
            float4 w0 = *(const float4*)wp;
            float4 w1 = *(const float4*)(wp + 4);
            uint4 u;
            u.x = pack_bf2(w0.x, w0.y);
            u.y = pack_bf2(w0.z, w0.w);
            u.z = pack_bf2(w1.x, w1.y);
            u.w = pack_bf2(w1.z, w1.w);
            *(uint4*)&Ws[r * 32 + ((cbA ^ (r & 3)) << 3)] = u;
        }
        __syncthreads();

        short8 af[4];
#pragma unroll
        for (int mb = 0; mb < 4; ++mb) {
            int row = wm * 64 + mb * 16 + lr;
            af[mb] = *(const short8*)&As[row * 32 + ((quad ^ (lr & 3)) << 3)];
        }
#pragma unroll
        for (int nb = 0; nb < 4; ++nb) {
            int row = wn * 64 + nb * 16 + lr;
            short8 bf = *(const short8*)&Ws[row * 32 + ((quad ^ (lr & 3)) << 3)];
#pragma unroll
            for (int mb = 0; mb < 4; ++mb)
                acc[mb][nb] = __builtin_amdgcn_mfma_f32_16x16x32_bf16(af[mb], bf, acc[mb][nb], 0, 0, 0);
        }
    }

    // C/D layout: col = lane&15, row = quad*4 + reg
#pragma unroll
    for (int mb = 0; mb < 4; ++mb)
#pragma unroll
        for (int nb = 0; nb < 4; ++nb) {
            int row = bm + wm * 64 + mb * 16 + quad * 4;
            int col = bn + wn * 64 + nb * 16 + lr;
#pragma unroll
            for (int r = 0; r < 4; ++r)
                C[(size_t)(row + r) * Dv + col] = acc[mb][nb][r];
        }
}

// ---------------------------------------------------------------------------
// Stage 3: LayerNorm in place on d_out (fp32). Biased variance, eps=1e-5.
// ---------------------------------------------------------------------------
__global__ __launch_bounds__(256)
void ln_kernel(float* __restrict__ C,
               const float* __restrict__ g) {
    const int row = blockIdx.x;
    const int t = threadIdx.x;
    const int wave = t >> 6, lane = t & 63;

    float* rp = C + (size_t)row * Dv;
    float4 x = *(const float4*)(rp + t * 4);

    float s = x.x + x.y + x.z + x.w;
    float sq = x.x * x.x + x.y * x.y + x.z * x.z + x.w * x.w;
#pragma unroll
    for (int off = 32; off >= 1; off >>= 1) {
        s += __shfl_xor(s, off);
        sq += __shfl_xor(sq, off);
    }
    __shared__ float ss[4], ssq[4];
    if (lane == 0) { ss[wave] = s; ssq[wave] = sq; }
    __syncthreads();
    s = ss[0] + ss[1] + ss[2] + ss[3];
    sq = ssq[0] + ssq[1] + ssq[2] + ssq[3];

    const float rn = 1.f / (float)Dv;
    float mean = s * rn;
    float var = sq * rn - mean * mean;
    float inv = rsqrtf(var + 1e-5f);

    float4 gv = *(const float4*)(g + t * 4);

    float4 o;
    o.x = (x.x - mean) * inv * gv.x;
    o.y = (x.y - mean) * inv * gv.y;
    o.z = (x.z - mean) * inv * gv.z;
    o.w = (x.w - mean) * inv * gv.w;
    *(float4*)(rp + t * 4) = o;
}

// ---------------------------------------------------------------------------
extern "C" void kernel_launch(void* const* d_in, const int* in_sizes, int n_in,
                              void* d_out, int out_size, void* d_ws, size_t ws_size,
                              hipStream_t stream) {
    const float* q = (const float*)d_in[0];
    const float* k = (const float*)d_in[1];
    const float* v = (const float*)d_in[2];
    const float* W = (const float*)d_in[3];
    const float* g = (const float*)d_in[4];
    float* out = (float*)d_out;

    __hip_bfloat16* attn = (__hip_bfloat16*)d_ws;   // [8192,1024] bf16 = 16.8 MB

    attn_mfma<<<dim3(Nv / 128, Hv, Bv), 256, 0, stream>>>(q, k, v, attn);
    proj_kernel<<<dim3(Dv / 128, (Bv * Nv) / 128), 256, 0, stream>>>(attn, W, out);
    ln_kernel<<<Bv * Nv, 256, 0, stream>>>(out, g);
}

// Round 6
// 338.430 us; speedup vs baseline: 1.2588x; 1.2588x over previous
//
#include <hip/hip_runtime.h>
#include <hip/hip_bf16.h>

// Problem: B=4, N=2048, H=16, Dh=64, D=1024. All global tensors fp32.
// out = LN( softmax(Q K^T / 8) V @ W_out^T ) * g   (fp32 out).
// R6: 1-instr v_perm bf16 packing, single-barrier double-buffered K/V
// pipeline (global latency hidden behind compute), Q frags from global,
// proj double-buffered + unswizzled (32-col rows are bank-uniform).

#define Bv 4
#define Nv 2048
#define Hv 16
#define DHv 64
#define Dv 1024
#define NT (Nv / 64)

typedef __attribute__((ext_vector_type(8))) short short8;
typedef __attribute__((ext_vector_type(4))) float floatx4;

// bf16 pair pack, round-half-up (+0x8000 then take high16 via one v_perm_b32).
__device__ inline unsigned pack_bf2(float a, float b) {
    unsigned ua = __builtin_bit_cast(unsigned, a) + 0x8000u;
    unsigned ub = __builtin_bit_cast(unsigned, b) + 0x8000u;
    return __builtin_amdgcn_perm(ub, ua, 0x07060302u);  // [b.hi16 : a.hi16]
}

// ---------------------------------------------------------------------------
// MFMA flash attention. Block = 256 thr (4 waves) = 128 queries of one (b,h).
// Q frags in registers (from global). K (swizzle row&7) and V^T (swizzle
// (d>>1)&7) double-buffered in LDS; one barrier per 64-key tile; tile i+1
// global loads issued before compute of tile i (vmcnt waits after compute).
// ---------------------------------------------------------------------------
__global__ __launch_bounds__(256)
void attn_mfma(const float* __restrict__ q,
               const float* __restrict__ k,
               const float* __restrict__ v,
               __hip_bfloat16* __restrict__ out) {
    __shared__ __align__(16) short Kt[2][64 * 64];   // 16 KB
    __shared__ __align__(16) short Vt[2][64 * 64];   // 16 KB (V^T: rows = d)

    const int t = threadIdx.x;
    const int wave = t >> 6, lane = t & 63;
    const int quad = lane >> 4, lr = lane & 15;
    const int b = blockIdx.z, h = blockIdx.y;
    const int q0 = blockIdx.x * 128;
    const size_t bh = ((size_t)b * Nv) * Dv + h * DHv;

    // ---- prefetch regs + staging lambdas ----
    float4 kpre[2][2], vpre[2][2];
    auto load_tile = [&](int k0) {
#pragma unroll
        for (int p = 0; p < 2; ++p) {
            int idx = p * 256 + t;
            int r = idx >> 3, cb = idx & 7;
            const float* kp = k + bh + (size_t)(k0 + r) * Dv + cb * 8;
            kpre[p][0] = *(const float4*)kp;
            kpre[p][1] = *(const float4*)(kp + 4);
            int dq = idx & 15, rr = idx >> 4;
            const float* vp = v + bh + (size_t)(k0 + 2 * rr) * Dv + dq * 4;
            vpre[p][0] = *(const float4*)vp;
            vpre[p][1] = *(const float4*)(vp + Dv);
        }
    };
    auto store_tile = [&](int buf) {
#pragma unroll
        for (int p = 0; p < 2; ++p) {
            int idx = p * 256 + t;
            int r = idx >> 3, cb = idx & 7;
            uint4 u;
            u.x = pack_bf2(kpre[p][0].x, kpre[p][0].y);
            u.y = pack_bf2(kpre[p][0].z, kpre[p][0].w);
            u.z = pack_bf2(kpre[p][1].x, kpre[p][1].y);
            u.w = pack_bf2(kpre[p][1].z, kpre[p][1].w);
            *(uint4*)&Kt[buf][r * 64 + ((cb ^ (r & 7)) << 3)] = u;
            int dq = idx & 15, rr = idx >> 4;
            float va[4] = {vpre[p][0].x, vpre[p][0].y, vpre[p][0].z, vpre[p][0].w};
            float vb[4] = {vpre[p][1].x, vpre[p][1].y, vpre[p][1].z, vpre[p][1].w};
#pragma unroll
            for (int i = 0; i < 4; ++i) {
                int d = dq * 4 + i;
                ((unsigned*)Vt[buf])[d * 32 + (((rr >> 2) ^ ((d >> 1) & 7)) << 2) + (rr & 3)] =
                    pack_bf2(va[i], vb[i]);
            }
        }
    };

    load_tile(0);   // start K/V tile-0 loads first

    // ---- Q fragments direct from global (once), scale 0.125 exact ----
    short8 qfrag[2][2];   // [qs][kh]: Q[q = q0+w*32+qs*16+lr][d = 32kh+8quad+j]
#pragma unroll
    for (int qs = 0; qs < 2; ++qs)
#pragma unroll
        for (int kh = 0; kh < 2; ++kh) {
            int row = q0 + wave * 32 + qs * 16 + lr;
            const float* qp = q + bh + (size_t)row * Dv + kh * 32 + quad * 8;
            float4 f0 = *(const float4*)qp;
            float4 f1 = *(const float4*)(qp + 4);
            int4 qi;
            qi.x = (int)pack_bf2(f0.x * 0.125f, f0.y * 0.125f);
            qi.y = (int)pack_bf2(f0.z * 0.125f, f0.w * 0.125f);
            qi.z = (int)pack_bf2(f1.x * 0.125f, f1.y * 0.125f);
            qi.w = (int)pack_bf2(f1.z * 0.125f, f1.w * 0.125f);
            qfrag[qs][kh] = __builtin_bit_cast(short8, qi);
        }

    store_tile(0);

    floatx4 o_acc[2][4] = {};        // [qs][td]: O[q=4quad+r][d=16td+lr]
    float mrow[2] = {-INFINITY, -INFINITY};
    float lrow[2] = {0.f, 0.f};
    const int srcA = ((2 * (quad & 1)) << 4) | lr;   // P-gather source lanes
    const int srcB = srcA + 16;
    const bool hi = (quad >= 2);

    for (int it = 0; it < NT; ++it) {
        const int cur = it & 1;
        __syncthreads();                         // buf[cur] fully staged
        if (it + 1 < NT) load_tile((it + 1) * 64);   // latency hidden by compute

        // ---- S^T = K·Q^T ----
        floatx4 s_acc[2][4] = {};
#pragma unroll
        for (int tt = 0; tt < 4; ++tt) {
            int row = tt * 16 + lr;
            short8 kf0 = *(const short8*)&Kt[cur][row * 64 + ((quad ^ (lr & 7)) << 3)];
            short8 kf1 = *(const short8*)&Kt[cur][row * 64 + (((4 + quad) ^ (lr & 7)) << 3)];
#pragma unroll
            for (int qs = 0; qs < 2; ++qs) {
                s_acc[qs][tt] = __builtin_amdgcn_mfma_f32_16x16x32_bf16(kf0, qfrag[qs][0], s_acc[qs][tt], 0, 0, 0);
                s_acc[qs][tt] = __builtin_amdgcn_mfma_f32_16x16x32_bf16(kf1, qfrag[qs][1], s_acc[qs][tt], 0, 0, 0);
            }
        }

        // ---- online softmax + P pack ----
        unsigned p2[2][8];
#pragma unroll
        for (int qs = 0; qs < 2; ++qs) {
            float tmax = -INFINITY;
#pragma unroll
            for (int tt = 0; tt < 4; ++tt)
#pragma unroll
                for (int r2 = 0; r2 < 4; ++r2) tmax = fmaxf(tmax, s_acc[qs][tt][r2]);
            tmax = fmaxf(tmax, __shfl_xor(tmax, 16));
            tmax = fmaxf(tmax, __shfl_xor(tmax, 32));
            float mnew = fmaxf(mrow[qs], tmax);
            float alpha = __expf(mrow[qs] - mnew);   // first tile: exp(-inf)=0
            mrow[qs] = mnew;
            float psum = 0.f;
#pragma unroll
            for (int tt = 0; tt < 4; ++tt)
#pragma unroll
                for (int r2 = 0; r2 < 4; ++r2) {
                    float p = __expf(s_acc[qs][tt][r2] - mnew);
                    s_acc[qs][tt][r2] = p;
                    psum += p;
                }
            psum += __shfl_xor(psum, 16);
            psum += __shfl_xor(psum, 32);
            lrow[qs] = lrow[qs] * alpha + psum;
#pragma unroll
            for (int r2 = 0; r2 < 4; ++r2) {
                float ar = __shfl(alpha, quad * 4 + r2);
#pragma unroll
                for (int td = 0; td < 4; ++td) o_acc[qs][td][r2] *= ar;
            }
#pragma unroll
            for (int tt = 0; tt < 4; ++tt) {
                p2[qs][tt * 2 + 0] = pack_bf2(s_acc[qs][tt][0], s_acc[qs][tt][1]);
                p2[qs][tt * 2 + 1] = pack_bf2(s_acc[qs][tt][2], s_acc[qs][tt][3]);
            }
        }

        // ---- PV: O += P·V ----
#pragma unroll
        for (int kh = 0; kh < 2; ++kh) {
            short8 af[2];
#pragma unroll
            for (int qs = 0; qs < 2; ++qs) {
                int tlo = 4 * kh, thi = 4 * kh + 2;
                unsigned d0a = __shfl(p2[qs][tlo + 0], srcA), d0b = __shfl(p2[qs][thi + 0], srcA);
                unsigned d1a = __shfl(p2[qs][tlo + 1], srcA), d1b = __shfl(p2[qs][thi + 1], srcA);
                unsigned d2a = __shfl(p2[qs][tlo + 0], srcB), d2b = __shfl(p2[qs][thi + 0], srcB);
                unsigned d3a = __shfl(p2[qs][tlo + 1], srcB), d3b = __shfl(p2[qs][thi + 1], srcB);
                int4 afi;
                afi.x = (int)(hi ? d0b : d0a);
                afi.y = (int)(hi ? d1b : d1a);
                afi.z = (int)(hi ? d2b : d2a);
                afi.w = (int)(hi ? d3b : d3a);
                af[qs] = __builtin_bit_cast(short8, afi);
            }
#pragma unroll
            for (int td = 0; td < 4; ++td) {
                int d = td * 16 + lr;
                short8 vf = *(const short8*)&Vt[cur][d * 64 + (((kh * 4 + quad) ^ (lr >> 1)) << 3)];
                o_acc[0][td] = __builtin_amdgcn_mfma_f32_16x16x32_bf16(af[0], vf, o_acc[0][td], 0, 0, 0);
                o_acc[1][td] = __builtin_amdgcn_mfma_f32_16x16x32_bf16(af[1], vf, o_acc[1][td], 0, 0, 0);
            }
        }

        if (it + 1 < NT) store_tile(1 - cur);    // cvt+write next tile (other buf)
    }

    // ---- epilogue: O / l -> bf16 ws (proj A-matrix) ----
#pragma unroll
    for (int qs = 0; qs < 2; ++qs) {
        float linv = 1.f / lrow[qs];
#pragma unroll
        for (int r2 = 0; r2 < 4; ++r2) {
            float lv = __shfl(linv, quad * 4 + r2);
            int row = q0 + wave * 32 + qs * 16 + quad * 4 + r2;
            size_t base = ((size_t)(b * Nv + row)) * Dv + h * DHv;
#pragma unroll
            for (int td = 0; td < 4; ++td)
                out[base + td * 16 + lr] = __float2bfloat16(o_acc[qs][td][r2] * lv);
        }
    }
}

// ---------------------------------------------------------------------------
// Stage 2: C = A @ W^T, 128x128 tile, BK=32, double-buffered LDS, 1 barrier
// per K-step. Unswizzled (32-col rows: bank = 16(row&1)+4quad+d, uniform).
// ---------------------------------------------------------------------------
__global__ __launch_bounds__(256)
void proj_kernel(const __hip_bfloat16* __restrict__ A,
                 const float* __restrict__ W,
                 float* __restrict__ C) {
    __shared__ __align__(16) short As[2][128 * 32];  // 16 KB
    __shared__ __align__(16) short Ws[2][128 * 32];  // 16 KB

    const int t = threadIdx.x;
    const int wave = t >> 6, lane = t & 63;
    const int quad = lane >> 4, lr = lane & 15;
    const int wm = wave >> 1, wn = wave & 1;
    const int bm = blockIdx.y * 128;
    const int bn = blockIdx.x * 128;

    floatx4 acc[4][4] = {};   // [mb][nb]

    const int rA = t >> 2;    // 0..63 (+64 for p=1)
    const int cbA = t & 3;

    uint4 apre[2];
    float4 wpre[2][2];
    auto load_t = [&](int k0) {
#pragma unroll
        for (int p = 0; p < 2; ++p) {
            int r = rA + p * 64;
            apre[p] = *(const uint4*)(A + (size_t)(bm + r) * Dv + k0 + cbA * 8);
            const float* wp = W + (size_t)(bn + r) * Dv + k0 + cbA * 8;
            wpre[p][0] = *(const float4*)wp;
            wpre[p][1] = *(const float4*)(wp + 4);
        }
    };
    auto store_t = [&](int buf) {
#pragma unroll
        for (int p = 0; p < 2; ++p) {
            int r = rA + p * 64;
            *(uint4*)&As[buf][r * 32 + cbA * 8] = apre[p];
            uint4 u;
            u.x = pack_bf2(wpre[p][0].x, wpre[p][0].y);
            u.y = pack_bf2(wpre[p][0].z, wpre[p][0].w);
            u.z = pack_bf2(wpre[p][1].x, wpre[p][1].y);
            u.w = pack_bf2(wpre[p][1].z, wpre[p][1].w);
            *(uint4*)&Ws[buf][r * 32 + cbA * 8] = u;
        }
    };

    load_t(0);
    store_t(0);

    for (int it = 0; it < Dv / 32; ++it) {
        const int cur = it & 1;
        __syncthreads();
        if (it + 1 < Dv / 32) load_t((it + 1) * 32);

        short8 af[4];
#pragma unroll
        for (int mb = 0; mb < 4; ++mb)
            af[mb] = *(const short8*)&As[cur][(wm * 64 + mb * 16 + lr) * 32 + quad * 8];
#pragma unroll
        for (int nb = 0; nb < 4; ++nb) {
            short8 bf = *(const short8*)&Ws[cur][(wn * 64 + nb * 16 + lr) * 32 + quad * 8];
#pragma unroll
            for (int mb = 0; mb < 4; ++mb)
                acc[mb][nb] = __builtin_amdgcn_mfma_f32_16x16x32_bf16(af[mb], bf, acc[mb][nb], 0, 0, 0);
        }

        if (it + 1 < Dv / 32) store_t(1 - cur);
    }

    // C/D layout: col = lane&15, row = quad*4 + reg
#pragma unroll
    for (int mb = 0; mb < 4; ++mb)
#pragma unroll
        for (int nb = 0; nb < 4; ++nb) {
            int row = bm + wm * 64 + mb * 16 + quad * 4;
            int col = bn + wn * 64 + nb * 16 + lr;
#pragma unroll
            for (int r = 0; r < 4; ++r)
                C[(size_t)(row + r) * Dv + col] = acc[mb][nb][r];
        }
}

// ---------------------------------------------------------------------------
// Stage 3: LayerNorm in place on d_out (fp32). Biased variance, eps=1e-5.
// ---------------------------------------------------------------------------
__global__ __launch_bounds__(256)
void ln_kernel(float* __restrict__ C,
               const float* __restrict__ g) {
    const int row = blockIdx.x;
    const int t = threadIdx.x;
    const int wave = t >> 6, lane = t & 63;

    float* rp = C + (size_t)row * Dv;
    float4 x = *(const float4*)(rp + t * 4);

    float s = x.x + x.y + x.z + x.w;
    float sq = x.x * x.x + x.y * x.y + x.z * x.z + x.w * x.w;
#pragma unroll
    for (int off = 32; off >= 1; off >>= 1) {
        s += __shfl_xor(s, off);
        sq += __shfl_xor(sq, off);
    }
    __shared__ float ss[4], ssq[4];
    if (lane == 0) { ss[wave] = s; ssq[wave] = sq; }
    __syncthreads();
    s = ss[0] + ss[1] + ss[2] + ss[3];
    sq = ssq[0] + ssq[1] + ssq[2] + ssq[3];

    const float rn = 1.f / (float)Dv;
    float mean = s * rn;
    float var = sq * rn - mean * mean;
    float inv = rsqrtf(var + 1e-5f);

    float4 gv = *(const float4*)(g + t * 4);

    float4 o;
    o.x = (x.x - mean) * inv * gv.x;
    o.y = (x.y - mean) * inv * gv.y;
    o.z = (x.z - mean) * inv * gv.z;
    o.w = (x.w - mean) * inv * gv.w;
    *(float4*)(rp + t * 4) = o;
}

// ---------------------------------------------------------------------------
extern "C" void kernel_launch(void* const* d_in, const int* in_sizes, int n_in,
                              void* d_out, int out_size, void* d_ws, size_t ws_size,
                              hipStream_t stream) {
    const float* q = (const float*)d_in[0];
    const float* k = (const float*)d_in[1];
    const float* v = (const float*)d_in[2];
    const float* W = (const float*)d_in[3];
    const float* g = (const float*)d_in[4];
    float* out = (float*)d_out;

    __hip_bfloat16* attn = (__hip_bfloat16*)d_ws;   // [8192,1024] bf16 = 16.8 MB

    attn_mfma<<<dim3(Nv / 128, Hv, Bv), 256, 0, stream>>>(q, k, v, attn);
    proj_kernel<<<dim3(Dv / 128, (Bv * Nv) / 128), 256, 0, stream>>>(attn, W, out);
    ln_kernel<<<Bv * Nv, 256, 0, stream>>>(out, g);
}